// Round 1
// 518.117 us; speedup vs baseline: 1.2158x; 1.2158x over previous
//
#include <hip/hip_runtime.h>
#include <cstdint>
#include <cstddef>

#define FEATURE_IN 4096
#define FEATURE_OUT 4096
#define RNK 16

typedef __bf16 bf16x8_t __attribute__((ext_vector_type(8)));
typedef __bf16 bf16x4_t __attribute__((ext_vector_type(4)));
typedef float f32x4_t __attribute__((ext_vector_type(4)));

// ============ prep kernel: blocks [0,NCVT) convert x fp32->bf16;
//              blocks [NCVT, NCVT+NFUSE) fold LoRA into W (bf16) =============
#define FW_KB 128
#define FW_NB 32
#define NCVT 16384            // M*K/8/256 = 8192*4096/2048
#define NFUSE 4096            // (K/FW_KB)*(N/FW_NB) = 32*128

__global__ __launch_bounds__(256) void prep_kernel(const float* __restrict__ x,
                                                   uint16_t* __restrict__ xb,
                                                   const float* __restrict__ w,
                                                   const float* __restrict__ la,
                                                   const float* __restrict__ lb,
                                                   uint16_t* __restrict__ wf) {
    __shared__ float las[FW_KB * RNK];     // [k][r], 8 KB
    __shared__ float lbs[RNK * FW_NB];     // [r][n], 2 KB

    const int tid = threadIdx.x;

    if (blockIdx.x < NCVT) {
        // ---- x fp32 -> bf16, 8 elems/thread, fully coalesced per instruction ----
        const int base = blockIdx.x * 512;           // float4 units
        const float4* xp = (const float4*)x;
        float4 v0 = xp[base + tid];                  // 64 lanes x 16B contiguous
        float4 v1 = xp[base + 256 + tid];
        bf16x4_t o0, o1;
        o0[0] = (__bf16)v0.x; o0[1] = (__bf16)v0.y; o0[2] = (__bf16)v0.z; o0[3] = (__bf16)v0.w;
        o1[0] = (__bf16)v1.x; o1[1] = (__bf16)v1.y; o1[2] = (__bf16)v1.z; o1[3] = (__bf16)v1.w;
        ((bf16x4_t*)xb)[base + tid] = o0;
        ((bf16x4_t*)xb)[base + 256 + tid] = o1;
        return;
    }

    // ---- Wf[n,k] = bf16(W[n,k] + 2*sum_r A[k,r]*B[r,n]), 128k x 32n tile ----
    const int bid = blockIdx.x - NCVT;
    const int kb = (bid & 31) * FW_KB;
    const int nb = (bid >> 5) * FW_NB;

    {
        const float4* src = (const float4*)(la + (size_t)kb * RNK);
        float4* dst = (float4*)las;
        dst[tid] = src[tid];
        dst[tid + 256] = src[tid + 256];
    }
#pragma unroll
    for (int f = tid; f < RNK * FW_NB; f += 256) {
        int r = f >> 5;
        int nl = f & 31;
        lbs[r * FW_NB + nl] = lb[(size_t)r * FEATURE_OUT + nb + nl];
    }
    __syncthreads();

    const int nl = tid >> 3;    // 0..31
    const int kq = tid & 7;     // 0..7, each covers 16 k

    f32x4_t bcol[4];
#pragma unroll
    for (int r4 = 0; r4 < 4; ++r4) {
        f32x4_t v;
#pragma unroll
        for (int j = 0; j < 4; ++j) v[j] = lbs[(r4 * 4 + j) * FW_NB + nl];
        bcol[r4] = v;
    }

    const f32x4_t* las4 = (const f32x4_t*)las;   // index k*4 + r4
    const float* wrow = w + (size_t)(nb + nl) * FEATURE_IN + kb + kq * 16;
    uint16_t* wfrow = wf + (size_t)(nb + nl) * FEATURE_IN + kb + kq * 16;

#pragma unroll
    for (int h = 0; h < 2; ++h) {          // two groups of 8 k
        float4 wv0 = ((const float4*)wrow)[h * 2 + 0];
        float4 wv1 = ((const float4*)wrow)[h * 2 + 1];
        float wfv[8] = {wv0.x, wv0.y, wv0.z, wv0.w, wv1.x, wv1.y, wv1.z, wv1.w};
        bf16x8_t o;
#pragma unroll
        for (int j = 0; j < 8; ++j) {
            const int k = kq * 16 + h * 8 + j;
            float s = 0.f;
#pragma unroll
            for (int rr = 0; rr < 4; ++rr) {
                const int r4 = (rr + kq) & 3;
                f32x4_t av = las4[k * 4 + r4];
                f32x4_t bv = bcol[r4];
                s += av[0] * bv[0] + av[1] * bv[1] + av[2] * bv[2] + av[3] * bv[3];
            }
            o[j] = (__bf16)(wfv[j] + 2.f * s);
        }
        ((bf16x8_t*)wfrow)[h] = o;
    }
}

// ======================= GEMM: 256x256 tile, 8-phase schedule =======================
// C[M,N] = Xb[M,K] * Wf[N,K]^T + bias.  8 waves (2M x 4N), BK=64, double-buffered
// 128 KiB LDS.  Per K-tile: 4 phases {ds_read frags | stage 1 half-tile | barrier |
// setprio(1) 16 MFMA setprio(0) | barrier}, counted vmcnt(4) at phases B/D (never 0
// in main loop).  Half-tiles are k-halves [256 rows][32 k] = 16 KB = 2 global_load_lds
// per thread.  LDS chunk placement row*64 + (((row>>1)+q)&3)*16 makes the 16-lane
// fragment read 2-way-aliased (free) without XOR-swizzled reads; staging stays linear
// (data permutation done on the per-lane GLOBAL source address).
#define BM 256
#define BN 256
#define BK 64
#define NT (FEATURE_IN / BK)   // 64 K-tiles

#define ABASE(P, KS) ((P) * 65536 + (KS) * 16384)
#define BBASE(P, KS) ((P) * 65536 + 32768 + (KS) * 16384)

#define READ_A(G, P, KS) do { _Pragma("unroll")                                          \
    for (int _mi = 0; _mi < 4; ++_mi)                                                    \
        a[_mi] = *(const bf16x8_t*)(lds + ABASE(P, KS) + aoff[(G) * 4 + _mi]); } while (0)

#define READ_B(P, KS) do { _Pragma("unroll")                                             \
    for (int _ni = 0; _ni < 4; ++_ni)                                                    \
        b[_ni] = *(const bf16x8_t*)(lds + BBASE(P, KS) + boff[_ni]); } while (0)

#define MFMA_G(G) do { _Pragma("unroll")                                                 \
    for (int _mi = 0; _mi < 4; ++_mi) { _Pragma("unroll")                                \
        for (int _ni = 0; _ni < 4; ++_ni)                                                \
            acc[(G) * 4 + _mi][_ni] = __builtin_amdgcn_mfma_f32_16x16x32_bf16(           \
                a[_mi], b[_ni], acc[(G) * 4 + _mi][_ni], 0, 0, 0); } } while (0)

#define STAGE_A(PN, KS) do {                                                             \
    __builtin_amdgcn_global_load_lds(                                                    \
        (const __attribute__((address_space(1))) void*)(pA0 + (KS) * 32),                \
        (__attribute__((address_space(3))) void*)(lds + ABASE(PN, KS) + wv * 1024),      \
        16, 0, 0);                                                                       \
    __builtin_amdgcn_global_load_lds(                                                    \
        (const __attribute__((address_space(1))) void*)(pA1 + (KS) * 32),                \
        (__attribute__((address_space(3))) void*)(lds + ABASE(PN, KS) + 8192 + wv * 1024),\
        16, 0, 0); } while (0)

#define STAGE_B(PN, KS) do {                                                             \
    __builtin_amdgcn_global_load_lds(                                                    \
        (const __attribute__((address_space(1))) void*)(pB0 + (KS) * 32),                \
        (__attribute__((address_space(3))) void*)(lds + BBASE(PN, KS) + wv * 1024),      \
        16, 0, 0);                                                                       \
    __builtin_amdgcn_global_load_lds(                                                    \
        (const __attribute__((address_space(1))) void*)(pB1 + (KS) * 32),                \
        (__attribute__((address_space(3))) void*)(lds + BBASE(PN, KS) + 8192 + wv * 1024),\
        16, 0, 0); } while (0)

#define PBAR() __builtin_amdgcn_s_barrier()
#define PRIO1 __builtin_amdgcn_s_setprio(1)
#define PRIO0 __builtin_amdgcn_s_setprio(0)
#define VMCNT(n) asm volatile("s_waitcnt vmcnt(" #n ")" ::: "memory")

// One K-tile (buffer P), staging the NEXT tile's 4 half-tiles into buffer PN.
#define TILE_BODY(P, PN)                                                                 \
    /* phase A */                                                                        \
    READ_A(0, P, 0); READ_B(P, 0);                                                       \
    STAGE_A(PN, 0);                                                                      \
    PBAR();                                                                              \
    PRIO1; MFMA_G(0); PRIO0;                                                             \
    PBAR();                                                                              \
    /* phase B */                                                                        \
    READ_A(1, P, 0);                                                                     \
    STAGE_B(PN, 0);                                                                      \
    PBAR();                                                                              \
    PRIO1; MFMA_G(1); PRIO0;                                                             \
    VMCNT(4);  /* retires prev tile's k-half1 pair; leaves 2 newest HTs in flight */     \
    PBAR();                                                                              \
    /* phase C */                                                                        \
    READ_A(0, P, 1); READ_B(P, 1);                                                       \
    STAGE_A(PN, 1);                                                                      \
    PBAR();                                                                              \
    PRIO1; MFMA_G(0); PRIO0;                                                             \
    PBAR();                                                                              \
    /* phase D */                                                                        \
    READ_A(1, P, 1);                                                                     \
    STAGE_B(PN, 1);                                                                      \
    PBAR();                                                                              \
    PRIO1; MFMA_G(1); PRIO0;                                                             \
    VMCNT(4);  /* retires next tile's k-half0 pair */                                    \
    PBAR();                                                                              \
    pA0 += BK; pA1 += BK; pB0 += BK; pB1 += BK;

__global__ __launch_bounds__(512, 2) void gemm256(const uint16_t* __restrict__ Au,
                                                  const uint16_t* __restrict__ Bu,
                                                  const float* __restrict__ bias,
                                                  float* __restrict__ C,
                                                  int M, int N, int K) {
    __shared__ __align__(16) char lds[131072];   // 2 bufs x (A 32K | B 32K)

    const __bf16* A = (const __bf16*)Au;
    const __bf16* B = (const __bf16*)Bu;

    const int tid  = threadIdx.x;
    const int wv   = tid >> 6;          // 0..7
    const int lane = tid & 63;
    const int waveM = wv >> 2;          // 0..1
    const int waveN = wv & 3;           // 0..3
    const int l15 = lane & 15;
    const int q   = lane >> 4;          // fragment k-chunk 0..3

    // T1: bijective XCD-chunk swizzle (nwg=512, 512%8==0)
    const int nbx = N / BN;
    const int nwg = nbx * (M / BM);
    const int bidlin = blockIdx.y * nbx + blockIdx.x;
    const int swz = (bidlin & 7) * (nwg >> 3) + (bidlin >> 3);
    const int by = swz / nbx;
    const int bx = swz - by * nbx;
    const int m0 = by * BM;
    const int n0 = bx * BN;

    // ---- per-thread staging source (chunk c = j*512+tid -> row c>>2, slot c&3) ----
    const int srow = tid >> 2;                       // 0..127 (load1: +128)
    const int sq   = ((tid & 3) - (srow >> 1)) & 3;  // logical chunk stored at this slot
    const __bf16* pA0 = A + (size_t)(m0 + srow) * K + sq * 8;
    const __bf16* pA1 = pA0 + (size_t)128 * K;
    const __bf16* pB0 = B + (size_t)(n0 + srow) * K + sq * 8;
    const __bf16* pB1 = pB0 + (size_t)128 * K;

    // ---- per-thread fragment LDS byte offsets (within a k-half block) ----
    int aoff[8], boff[4];
#pragma unroll
    for (int mi = 0; mi < 8; ++mi) {
        int row = waveM * 128 + mi * 16 + l15;
        aoff[mi] = row * 64 + (((row >> 1) + q) & 3) * 16;
    }
#pragma unroll
    for (int ni = 0; ni < 4; ++ni) {
        int row = waveN * 64 + ni * 16 + l15;
        boff[ni] = row * 64 + (((row >> 1) + q) & 3) * 16;
    }

    f32x4_t acc[8][4];
#pragma unroll
    for (int mi = 0; mi < 8; ++mi)
#pragma unroll
        for (int ni = 0; ni < 4; ++ni)
            acc[mi][ni] = (f32x4_t)0.f;

    bf16x8_t a[4], b[4];

    // ---- prologue: stage tile 0 into buf0, keep its k-half1 pair in flight ----
    STAGE_A(0, 0); STAGE_B(0, 0); STAGE_A(0, 1); STAGE_B(0, 1);
    pA0 += BK; pA1 += BK; pB0 += BK; pB1 += BK;
    VMCNT(4);
    PBAR();

    // ---- main loop: tiles 0..61 (staging 1..62) ----
#pragma unroll 1
    for (int i = 0; i < (NT - 2) / 2; ++i) {
        TILE_BODY(0, 1)
        TILE_BODY(1, 0)
    }
    // tile 62 (buf0), stages tile 63 into buf1
    TILE_BODY(0, 1)

    // ---- epilogue tile 63 (buf1), no staging; drain remaining loads ----
    READ_A(0, 1, 0); READ_B(1, 0);
    PRIO1; MFMA_G(0); PRIO0;
    READ_A(1, 1, 0);
    PRIO1; MFMA_G(1); PRIO0;
    VMCNT(0);
    PBAR();
    READ_A(0, 1, 1); READ_B(1, 1);
    PRIO1; MFMA_G(0); PRIO0;
    READ_A(1, 1, 1);
    PRIO1; MFMA_G(1); PRIO0;

    // ---- C write: D layout col=lane&15, row=q*4+j ----
#pragma unroll
    for (int ni = 0; ni < 4; ++ni) {
        const int col = n0 + waveN * 64 + ni * 16 + l15;
        const float bv = bias[col];
#pragma unroll
        for (int mi = 0; mi < 8; ++mi) {
            const int row = m0 + waveM * 128 + mi * 16 + q * 4;
            float* op = C + (size_t)row * N + col;
#pragma unroll
            for (int j = 0; j < 4; ++j)
                op[(size_t)j * N] = acc[mi][ni][j] + bv;
        }
    }
}

extern "C" void kernel_launch(void* const* d_in, const int* in_sizes, int n_in,
                              void* d_out, int out_size, void* d_ws, size_t ws_size,
                              hipStream_t stream) {
    const float* x  = (const float*)d_in[0];   // [4,2048,4096]
    const float* w  = (const float*)d_in[1];   // [4096,4096]  (out,in)
    const float* b  = (const float*)d_in[2];   // [4096]
    const float* la = (const float*)d_in[3];   // [4096,16]
    const float* lb = (const float*)d_in[4];   // [16,4096]
    float* out = (float*)d_out;

    const int M = in_sizes[0] / FEATURE_IN;    // 8192
    const int K = FEATURE_IN;
    const int N = FEATURE_OUT;

    uint16_t* xb = (uint16_t*)d_ws;                                  // M*K bf16 = 64 MiB
    uint16_t* wf = (uint16_t*)((char*)d_ws + (size_t)M * K * 2);     // N*K bf16 = 32 MiB

    // 1) fused prep: x->bf16 + LoRA-folded W->bf16 (one dispatch)
    prep_kernel<<<NCVT + NFUSE, 256, 0, stream>>>(x, xb, w, la, lb, wf);

    // 2) GEMM + bias, 256x256 8-phase
    {
        dim3 grid(N / BN, M / BM);   // (16, 32)
        gemm256<<<grid, 512, 0, stream>>>(xb, wf, b, out, M, N, K);
    }
}